// Round 5
// baseline (291.223 us; speedup 1.0000x reference)
//
#include <hip/hip_runtime.h>
#include <hip/hip_bf16.h>
#include <cstdint>
#include <cstddef>

typedef __hip_bfloat16 bf16;
using short8 = __attribute__((ext_vector_type(8))) short;
using f32x4  = __attribute__((ext_vector_type(4))) float;

static constexpr int   kNC    = 1026;   // n_fft + 2 (real S_ri cols)
static constexpr int   kKS    = 1152;   // padded S_ri cols (18*64)
static constexpr float kTwoPi = 6.283185307179586f;

#define GLDS(g, l) __builtin_amdgcn_global_load_lds(                       \
    (const __attribute__((address_space(1))) uint32_t*)(g),                \
    (__attribute__((address_space(3))) uint32_t*)(l), 16, 0, 0)

#define BAR()   { __builtin_amdgcn_sched_barrier(0); __builtin_amdgcn_s_barrier(); }
#define LGKM0() { asm volatile("s_waitcnt lgkmcnt(0)" ::: "memory"); __builtin_amdgcn_sched_barrier(0); }
#define VM8()   { asm volatile("s_waitcnt vmcnt(8)" ::: "memory"); __builtin_amdgcn_sched_barrier(0); }
#define VM0()   { asm volatile("s_waitcnt vmcnt(0)" ::: "memory"); __builtin_amdgcn_sched_barrier(0); }

// ---------------------------------------------------------------- prep: x -> bf16
__global__ void cvt_x_k(const float* __restrict__ x, bf16* __restrict__ xb) {
    size_t i = ((size_t)blockIdx.x * 256 + threadIdx.x) * 8;
    float4 a = *(const float4*)(x + i);
    float4 c = *(const float4*)(x + i + 4);
    union { bf16 h[8]; uint4 u; } o;
    o.h[0] = __float2bfloat16(a.x); o.h[1] = __float2bfloat16(a.y);
    o.h[2] = __float2bfloat16(a.z); o.h[3] = __float2bfloat16(a.w);
    o.h[4] = __float2bfloat16(c.x); o.h[5] = __float2bfloat16(c.y);
    o.h[6] = __float2bfloat16(c.z); o.h[7] = __float2bfloat16(c.w);
    *(uint4*)(xb + i) = o.u;
}

// ------------------------------------------- prep: W -> Wr [1152][512] interleaved
__global__ void prep_w_k(const float* __restrict__ W, const float* __restrict__ b,
                         bf16* __restrict__ Wr, float* __restrict__ br) {
    int j = blockIdx.x;
    int col = -1;
    if (j < 1024)      col = (j & 1) ? 513 + (j >> 1) : (j >> 1);
    else if (j == 1024) col = 512;
    else if (j == 1025) col = 1025;
    for (int k = threadIdx.x; k < 512; k += 256) {
        float v = (col >= 0) ? W[(size_t)k * 1026 + col] : 0.0f;
        Wr[(size_t)j * 512 + k] = __float2bfloat16(v);
    }
    if (threadIdx.x == 0) br[j] = (col >= 0) ? b[col] : 0.0f;
}

// --------------------- prep: windowed irfft matrix Mw [1024 rows n][1152 cols kk]
__global__ void prep_m_k(bf16* __restrict__ Mw, float* __restrict__ w2) {
    int nrow = blockIdx.x;
    float wn = 0.5f - 0.5f * cosf(kTwoPi * (float)nrow / 1023.0f);  // numpy hanning
    for (int kk = threadIdx.x; kk < 1152; kk += 256) {
        float v = 0.0f;
        if (kk < 1026) {
            int k = kk >> 1;
            int mm = (k * nrow) & 1023;
            float ang = kTwoPi * (float)mm * (1.0f / 1024.0f);
            float alpha = (k == 0 || k == 512) ? 1.0f : 2.0f;
            float tw = (kk & 1) ? -sinf(ang) : cosf(ang);
            v = alpha * (1.0f / 1024.0f) * wn * tw;
        }
        Mw[(size_t)nrow * 1152 + kk] = __float2bfloat16(v);
    }
    if (threadIdx.x == 0) w2[nrow] = wn * wn;
}

// ---------------------------------------------------- 256x128 bf16 GEMM, B-from-L2
// C = A(MxK) * B^T (B stored [n][k]); BK=64; 4 waves (2M x 2N), per-wave 128x64.
// LDS: A only, 2 bufs x [256][64] bf16 = 64 KB -> 2 blocks/CU (cross-block overlap).
// B fragments loaded straight from global (panel is L2-resident).
// Counted vmcnt(8): stage(t+2) stays in flight across the barrier.
template<int K, int LDO, int EPI, int NTILES>
__global__ __launch_bounds__(256, 2)
void gemmv5_k(const bf16* __restrict__ A, const bf16* __restrict__ B,
              const float* __restrict__ bias, bf16* __restrict__ O)
{
    __shared__ __align__(16) bf16 lsA[2][256 * 64];
    constexpr int NT = K / 64;          // 8 (GEMM1) or 18 (GEMM2), even

    const int tid  = threadIdx.x;
    const int w    = tid >> 6;
    const int lane = tid & 63;
    const int wr = w >> 1, wc = w & 1;

    const int nwg  = gridDim.x;
    const int orig = blockIdx.x;
    const int bid  = (orig & 7) * (nwg >> 3) + (orig >> 3);   // XCD-contiguous
    const int nt = bid % NTILES;        // nt-minor: chunk keeps A-panel L2-hot
    const int mt = bid / NTILES;
    const int row0 = mt * 256;
    const int col0 = nt * 128;

    const int srow  = lane >> 3;
    const int sslot = (lane & 7) ^ srow;          // pre-swizzled global 16B slot

    const bf16* gA = A + (size_t)(row0 + srow) * K + sslot * 8;
    const bf16* gB = B + (size_t)(col0 + wc * 64 + (lane & 15)) * K + (lane >> 4) * 8;

    auto stage = [&](int t, int buf) {
        #pragma unroll
        for (int l = 0; l < 8; ++l) {
            const int c = w * 8 + l;              // 8-row chunk
            GLDS(gA + (size_t)(c * 8) * K + (size_t)t * 64,
                 &lsA[buf][c * 512 + lane * 8]);
        }
    };

    short8 af[8][2], bq[4][2];
    auto loadaf = [&](int buf) {
        #pragma unroll
        for (int fm = 0; fm < 8; ++fm)
            #pragma unroll
            for (int ks = 0; ks < 2; ++ks) {
                const int r = wr * 128 + fm * 16 + (lane & 15);
                const int s = ks * 4 + (lane >> 4);
                af[fm][ks] = *(const short8*)(&lsA[buf][r * 64 + ((s ^ (r & 7)) << 3)]);
            }
    };
    auto loadbq = [&](int t) {
        #pragma unroll
        for (int fn = 0; fn < 4; ++fn)
            #pragma unroll
            for (int ks = 0; ks < 2; ++ks)
                bq[fn][ks] = *(const short8*)(gB + (size_t)fn * 16 * K
                                                 + (size_t)t * 64 + ks * 32);
    };

    f32x4 acc[8][4] = {};

    #define MMA() do {                                                         \
        __builtin_amdgcn_s_setprio(1);                                         \
        _Pragma("unroll") for (int ks = 0; ks < 2; ++ks)                       \
          _Pragma("unroll") for (int fm = 0; fm < 8; ++fm)                     \
            _Pragma("unroll") for (int fn = 0; fn < 4; ++fn)                   \
              acc[fm][fn] = __builtin_amdgcn_mfma_f32_16x16x32_bf16(           \
                  af[fm][ks], bq[fn][ks], acc[fm][fn], 0, 0, 0);               \
        __builtin_amdgcn_s_setprio(0); } while (0)

    // prologue: stage t0->buf0, bq(0), stage t1->buf1; retire t0+bq0, keep t1 in flight
    stage(0, 0); loadbq(0); stage(1, 1);
    VM8(); BAR();

    for (int t = 0; t + 2 < NT; ++t) {
        loadaf(t & 1);
        LGKM0(); BAR();                 // all waves done reading buf(t&1)
        stage(t + 2, t & 1);            // recycle slab; loads stay in flight
        VM8();                          // retire stage(t+1)+bq(t); keep stage(t+2)
        BAR();                          // slab t+1 visible
        MMA();
        loadbq(t + 1);                  // L2 latency hides under next phase
    }
    {   // t = NT-2: no stage(NT) -> must drain to reach bq(NT-2)
        loadaf(NT & 1);                 // (NT-2)&1 == NT&1 for even NT
        LGKM0(); BAR();
        VM0();
        BAR();
        MMA();
        loadbq(NT - 1);
    }
    {   // t = NT-1: nothing outstanding except bq(NT-1)
        loadaf((NT - 1) & 1);
        LGKM0();
        VM0();
        MMA();
    }
    #undef MMA

    // ------------------------------------------------------------------ epilogue
    const int mb = row0 + wr * 128;
    const int nb = col0 + wc * 64;
    #pragma unroll
    for (int fm = 0; fm < 8; ++fm) {
        #pragma unroll
        for (int fn = 0; fn < 4; ++fn) {
            const int n = nb + fn * 16 + (lane & 15);
            #pragma unroll
            for (int r = 0; r < 4; ++r) {
                const int m = mb + fm * 16 + (lane >> 4) * 4 + r;
                float v = acc[fm][fn][r];
                if constexpr (EPI == 1) {
                    v += bias[n];
                    float vo = __shfl_xor(v, 1);
                    float res = (n & 1) ? fminf(__expf(vo), 100.0f) * __sinf(v)
                                        : fminf(__expf(v), 100.0f) * __cosf(vo);
                    if (n < kNC)
                        O[(size_t)m * LDO + n] = __float2bfloat16(res);
                    else if (n < kKS)
                        O[(size_t)m * LDO + n] = __float2bfloat16(0.0f);
                } else {
                    O[(size_t)m * LDO + n] = __float2bfloat16(v);
                }
            }
        }
    }
}

// ------------------------------------------------------------- overlap-add gather
__global__ void ola_k(const bf16* __restrict__ frames, const float* __restrict__ w2g,
                      float* __restrict__ out) {
    __shared__ float w2[1024];
    for (int i = threadIdx.x; i < 1024; i += 256) w2[i] = w2g[i];
    __syncthreads();
    int o  = blockIdx.x * 256 + threadIdx.x;
    int b  = o >> 19;
    int oo = o & 524287;
    int s  = oo + 384;
    int tmax = s >> 8;
    float sum = 0.0f, env = 0.0f;
    #pragma unroll
    for (int jj = 0; jj < 4; ++jj) {
        int t = tmax - jj;
        if (t >= 0 && t < 2048) {
            int n = s - (t << 8);
            sum += __bfloat162float(frames[(((size_t)b * 2048 + t) << 10) + n]);
            env += w2[n];
        }
    }
    out[o] = sum / (env + 1e-11f);
}

// ---------------------------------------------------------------------- launcher
extern "C" void kernel_launch(void* const* d_in, const int* in_sizes, int n_in,
                              void* d_out, int out_size, void* d_ws, size_t ws_size,
                              hipStream_t stream)
{
    const float* x = (const float*)d_in[0];
    const float* W = (const float*)d_in[1];
    const float* b = (const float*)d_in[2];
    float* out = (float*)d_out;

    char* ws = (char*)d_ws;
    size_t off = 0;
    auto alloc = [&](size_t bytes) { char* p = ws + off; off += (bytes + 255) & ~255ull; return p; };

    bf16*  Mw  = (bf16*) alloc(1024ull * 1152 * 2);
    float* w2  = (float*)alloc(1024 * 4);
    float* br  = (float*)alloc(1152 * 4);
    bf16*  Sri = (bf16*) alloc(32768ull * 1152 * 2);   // (Re,Im) interleaved, K-padded
    char*  regC = alloc(67108864ull);
    bf16*  xb     = (bf16*)regC;
    bf16*  Wr     = (bf16*)(regC + 33554432ull);       // [1152][512]
    bf16*  frames = (bf16*)regC;                       // aliases xb+Wr after GEMM1

    cvt_x_k <<<dim3(8192), dim3(256), 0, stream>>>(x, xb);
    prep_w_k<<<dim3(1152), dim3(256), 0, stream>>>(W, b, Wr, br);
    prep_m_k<<<dim3(1024), dim3(256), 0, stream>>>(Mw, w2);
    // GEMM1: (32768 x 1152) = xb @ Wr^T, fused exp/cos/sin -> Sri (LDO 1152)
    gemmv5_k<512, 1152, 1, 9> <<<dim3(1152), dim3(256), 0, stream>>>(xb, Wr, br, Sri);
    // GEMM2: (32768 x 1024) = Sri @ Mw^T -> windowed frames
    gemmv5_k<1152, 1024, 0, 8><<<dim3(1024), dim3(256), 0, stream>>>(Sri, Mw, nullptr, frames);
    ola_k   <<<dim3(32768), dim3(256), 0, stream>>>(frames, w2, out);
    (void)in_sizes; (void)n_in; (void)out_size; (void)ws_size;
}

// Round 6
// 233.736 us; speedup vs baseline: 1.2459x; 1.2459x over previous
//
#include <hip/hip_runtime.h>
#include <hip/hip_bf16.h>
#include <cstdint>
#include <cstddef>

typedef __hip_bfloat16 bf16;
using short8 = __attribute__((ext_vector_type(8))) short;
using f32x4  = __attribute__((ext_vector_type(4))) float;

static constexpr int   kNC    = 1026;   // n_fft + 2 (real S_ri cols)
static constexpr float kTwoPi = 6.283185307179586f;

#define GLDS(g, l) __builtin_amdgcn_global_load_lds(                       \
    (const __attribute__((address_space(1))) uint32_t*)(g),                \
    (__attribute__((address_space(3))) uint32_t*)(l), 16, 0, 0)

// ---------------------------------------------------------------- prep: x -> bf16
__global__ void cvt_x_k(const float* __restrict__ x, bf16* __restrict__ xb) {
    size_t i = ((size_t)blockIdx.x * 256 + threadIdx.x) * 8;
    float4 a = *(const float4*)(x + i);
    float4 c = *(const float4*)(x + i + 4);
    union { bf16 h[8]; uint4 u; } o;
    o.h[0] = __float2bfloat16(a.x); o.h[1] = __float2bfloat16(a.y);
    o.h[2] = __float2bfloat16(a.z); o.h[3] = __float2bfloat16(a.w);
    o.h[4] = __float2bfloat16(c.x); o.h[5] = __float2bfloat16(c.y);
    o.h[6] = __float2bfloat16(c.z); o.h[7] = __float2bfloat16(c.w);
    *(uint4*)(xb + i) = o.u;
}

// ------------------------------------------- prep: W -> Wr [1280][512] interleaved
__global__ void prep_w_k(const float* __restrict__ W, const float* __restrict__ b,
                         bf16* __restrict__ Wr, float* __restrict__ br) {
    int j = blockIdx.x;
    int col = -1;
    if (j < 1024)      col = (j & 1) ? 513 + (j >> 1) : (j >> 1);
    else if (j == 1024) col = 512;
    else if (j == 1025) col = 1025;
    for (int k = threadIdx.x; k < 512; k += 256) {
        float v = (col >= 0) ? W[(size_t)k * 1026 + col] : 0.0f;
        Wr[(size_t)j * 512 + k] = __float2bfloat16(v);
    }
    if (threadIdx.x == 0) br[j] = (col >= 0) ? b[col] : 0.0f;
}

// --------------------- prep: windowed irfft matrix Mw [1024 rows n][1088 cols kk]
__global__ void prep_m_k(bf16* __restrict__ Mw, float* __restrict__ w2) {
    int nrow = blockIdx.x;
    float wn = 0.5f - 0.5f * cosf(kTwoPi * (float)nrow / 1023.0f);  // numpy hanning
    for (int kk = threadIdx.x; kk < 1088; kk += 256) {
        float v = 0.0f;
        if (kk < 1026) {
            int k = kk >> 1;
            int mm = (k * nrow) & 1023;
            float ang = kTwoPi * (float)mm * (1.0f / 1024.0f);
            float alpha = (k == 0 || k == 512) ? 1.0f : 2.0f;
            float tw = (kk & 1) ? -sinf(ang) : cosf(ang);
            v = alpha * (1.0f / 1024.0f) * wn * tw;
        }
        Mw[(size_t)nrow * 1088 + kk] = __float2bfloat16(v);
    }
    if (threadIdx.x == 0) w2[nrow] = wn * wn;
}

// ------------------------------------------------- 256x256 deep-pipelined bf16 GEMM
// K-loop identical to R3 (107us, 0 conflicts). NEW: epilogue transposes acc through
// LDS (reusing the 128KiB staging buffer, XOR-swizzled) and writes O with fully
// coalesced global_store_dwordx4 (2 x 512B segments per wave-instr) instead of
// 128 scattered 2B stores per thread.
template<int K, int LDO, int EPI, int MT>
__global__ __launch_bounds__(512, 2)
void gemm256_k(const bf16* __restrict__ A, const bf16* __restrict__ B,
               const float* __restrict__ bias, bf16* __restrict__ O)
{
    extern __shared__ bf16 lds[];            // [2][32768] : A 16384 | B 16384 per slab
    constexpr int NT = K / 64;

    const int tid  = threadIdx.x;
    const int w    = tid >> 6;
    const int lane = tid & 63;
    const int wr = w >> 2, wc = w & 3;       // wave grid 2 (M) x 4 (N)

    const int nwg  = gridDim.x;
    const int orig = blockIdx.x;
    const int bid  = (orig & 7) * (nwg >> 3) + (orig >> 3);   // XCD-contiguous chunks
    const int mt = bid % MT;
    const int nt = bid / MT;
    const int row0 = mt * 256;
    const int col0 = nt * 256;

    const int srow  = lane >> 3;             // row within chunk (== row & 7)
    const int sslot = (lane & 7) ^ srow;     // pre-swizzled global 16B-slot

    const bf16* gA0 = A + (size_t)(row0 + srow) * K + sslot * 8;
    const bf16* gB0 = B + (size_t)(col0 + srow) * K + sslot * 8;

    auto stage = [&](int t, int s) {
        bf16* lA = lds + s * 32768;
        bf16* lB = lA + 16384;
        #pragma unroll
        for (int l = 0; l < 4; ++l) {
            const int c = w * 4 + l;
            GLDS(gA0 + (size_t)(8 * c) * K + t * 64, lA + c * 512 + lane * 8);
            GLDS(gB0 + (size_t)(8 * c) * K + t * 64, lB + c * 512 + lane * 8);
        }
    };

    f32x4 acc[8][4] = {};

    stage(0, 0);
    if (NT > 1) stage(1, 1);
    asm volatile("s_waitcnt vmcnt(8)" ::: "memory");
    __builtin_amdgcn_sched_barrier(0);
    __builtin_amdgcn_s_barrier();
    asm volatile("" ::: "memory");

    for (int t = 0; t < NT; ++t) {
        bf16* lA = lds + (t & 1) * 32768;
        bf16* lB = lA + 16384;

        short8 bq[4][2];
        #pragma unroll
        for (int fn = 0; fn < 4; ++fn)
            #pragma unroll
            for (int ks = 0; ks < 2; ++ks) {
                const int row = wc * 64 + fn * 16 + (lane & 15);
                const int sl  = (ks * 4 + (lane >> 4)) ^ (row & 7);
                bq[fn][ks] = *(const short8*)(lB + row * 64 + sl * 8);
            }

        #pragma unroll
        for (int q = 0; q < 4; ++q) {
            short8 af[2][2];
            #pragma unroll
            for (int i = 0; i < 2; ++i)
                #pragma unroll
                for (int ks = 0; ks < 2; ++ks) {
                    const int row = wr * 128 + (q * 2 + i) * 16 + (lane & 15);
                    const int sl  = (ks * 4 + (lane >> 4)) ^ (row & 7);
                    af[i][ks] = *(const short8*)(lA + row * 64 + sl * 8);
                }
            if (q == 3) {
                asm volatile("s_waitcnt lgkmcnt(0)" ::: "memory");
                __builtin_amdgcn_sched_barrier(0);
                __builtin_amdgcn_s_barrier();        // all waves done reading slab
                asm volatile("" ::: "memory");
                if (t + 2 < NT) {
                    stage(t + 2, t & 1);             // recycle slab; loads stay in flight
                    asm volatile("s_waitcnt vmcnt(8)" ::: "memory");   // tile t+1 resident
                } else if (t + 1 < NT) {
                    asm volatile("s_waitcnt vmcnt(0)" ::: "memory");   // epilogue drain
                }
                __builtin_amdgcn_sched_barrier(0);
                __builtin_amdgcn_s_barrier();        // next slab visible to all waves
                asm volatile("" ::: "memory");
            }
            __builtin_amdgcn_s_setprio(1);
            #pragma unroll
            for (int i = 0; i < 2; ++i)
                #pragma unroll
                for (int fn = 0; fn < 4; ++fn)
                    #pragma unroll
                    for (int ks = 0; ks < 2; ++ks)
                        acc[q * 2 + i][fn] = __builtin_amdgcn_mfma_f32_16x16x32_bf16(
                            af[i][ks], bq[fn][ks], acc[q * 2 + i][fn], 0, 0, 0);
            __builtin_amdgcn_s_setprio(0);
        }
    }

    // --------------------------- epilogue: acc -> LDS (swizzled) -> coalesced store
    asm volatile("s_waitcnt lgkmcnt(0) vmcnt(0)" ::: "memory");
    __builtin_amdgcn_sched_barrier(0);
    __builtin_amdgcn_s_barrier();            // safe to overwrite staging LDS
    asm volatile("" ::: "memory");

    char* eb = (char*)lds;                   // [256 rows][512 B], 16B-slot XOR swizzle
    #pragma unroll
    for (int fm = 0; fm < 8; ++fm) {
        #pragma unroll
        for (int fn = 0; fn < 4; ++fn) {
            const int col = wc * 64 + fn * 16 + (lane & 15);     // 0..255 in tile
            const int n   = col0 + col;
            #pragma unroll
            for (int r = 0; r < 4; ++r) {
                const int row = wr * 128 + fm * 16 + (lane >> 4) * 4 + r;
                float v = acc[fm][fn][r];
                bf16 val;
                if constexpr (EPI == 1) {
                    v += bias[n];
                    float vo = __shfl_xor(v, 1);
                    float res = (n & 1) ? fminf(__expf(vo), 100.0f) * __sinf(v)
                                        : fminf(__expf(v), 100.0f) * __cosf(vo);
                    val = __float2bfloat16(n < kNC ? res : 0.0f);
                } else {
                    val = __float2bfloat16(v);
                }
                const int sw = (col >> 3) ^ (((row >> 2) & 7) << 1);
                *(bf16*)(eb + row * 512 + sw * 16 + (col & 7) * 2) = val;
            }
        }
    }
    asm volatile("s_waitcnt lgkmcnt(0)" ::: "memory");
    __builtin_amdgcn_sched_barrier(0);
    __builtin_amdgcn_s_barrier();
    asm volatile("" ::: "memory");

    #pragma unroll
    for (int k2 = 0; k2 < 16; ++k2) {
        const int g   = tid + k2 * 512;      // 0..8191 16B-chunks, global-coalesced
        const int row = g >> 5;
        const int s   = g & 31;
        const int sw  = s ^ (((row >> 2) & 7) << 1);
        short8 vv = *(const short8*)(eb + row * 512 + sw * 16);
        const int colg = col0 + s * 8;
        if (colg < LDO)                       // clip GEMM1's nt=4 padding tile
            *(short8*)(O + (size_t)(row0 + row) * LDO + colg) = vv;
    }
}

// ------------------------------------------------------------- overlap-add gather
__global__ void ola_k(const bf16* __restrict__ frames, const float* __restrict__ w2g,
                      float* __restrict__ out) {
    __shared__ float w2[1024];
    for (int i = threadIdx.x; i < 1024; i += 256) w2[i] = w2g[i];
    __syncthreads();
    int o  = blockIdx.x * 256 + threadIdx.x;
    int b  = o >> 19;
    int oo = o & 524287;
    int s  = oo + 384;
    int tmax = s >> 8;
    float sum = 0.0f, env = 0.0f;
    #pragma unroll
    for (int jj = 0; jj < 4; ++jj) {
        int t = tmax - jj;
        if (t >= 0 && t < 2048) {
            int n = s - (t << 8);
            sum += __bfloat162float(frames[(((size_t)b * 2048 + t) << 10) + n]);
            env += w2[n];
        }
    }
    out[o] = sum / (env + 1e-11f);
}

// ---------------------------------------------------------------------- launcher
extern "C" void kernel_launch(void* const* d_in, const int* in_sizes, int n_in,
                              void* d_out, int out_size, void* d_ws, size_t ws_size,
                              hipStream_t stream)
{
    const float* x = (const float*)d_in[0];
    const float* W = (const float*)d_in[1];
    const float* b = (const float*)d_in[2];
    float* out = (float*)d_out;

    char* ws = (char*)d_ws;
    size_t off = 0;
    auto alloc = [&](size_t bytes) { char* p = ws + off; off += (bytes + 255) & ~255ull; return p; };

    bf16*  Mw  = (bf16*) alloc(1024ull * 1088 * 2);
    float* w2  = (float*)alloc(1024 * 4);
    float* br  = (float*)alloc(1280 * 4);
    bf16*  Sri = (bf16*) alloc(32768ull * 1088 * 2);   // (Re,Im) interleaved, K-padded
    char*  regC = alloc(67108864ull);
    bf16*  xb     = (bf16*)regC;
    bf16*  Wr     = (bf16*)(regC + 33554432ull);       // [1280][512]
    bf16*  frames = (bf16*)regC;                       // aliases xb+Wr after GEMM1

    hipFuncSetAttribute(reinterpret_cast<const void*>(gemm256_k<512, 1088, 1, 128>),
                        hipFuncAttributeMaxDynamicSharedMemorySize, 131072);
    hipFuncSetAttribute(reinterpret_cast<const void*>(gemm256_k<1088, 1024, 0, 128>),
                        hipFuncAttributeMaxDynamicSharedMemorySize, 131072);

    cvt_x_k <<<dim3(8192), dim3(256), 0, stream>>>(x, xb);
    prep_w_k<<<dim3(1280), dim3(256), 0, stream>>>(W, b, Wr, br);
    prep_m_k<<<dim3(1024), dim3(256), 0, stream>>>(Mw, w2);
    // GEMM1: (32768 x 1280) = xb @ Wr^T, fused exp/cos/sin -> Sri (LDO 1088)
    gemm256_k<512, 1088, 1, 128><<<dim3(640), dim3(512), 131072, stream>>>(xb, Wr, br, Sri);
    // GEMM2: (32768 x 1024) = Sri @ Mw^T -> windowed frames
    gemm256_k<1088, 1024, 0, 128><<<dim3(512), dim3(512), 131072, stream>>>(Sri, Mw, nullptr, frames);
    ola_k   <<<dim3(32768), dim3(256), 0, stream>>>(frames, w2, out);
    (void)in_sizes; (void)n_in; (void)out_size; (void)ws_size;
}

// Round 8
// 202.283 us; speedup vs baseline: 1.4397x; 1.1555x over previous
//
#include <hip/hip_runtime.h>
#include <hip/hip_bf16.h>
#include <cstdint>
#include <cstddef>

typedef __hip_bfloat16 bf16;
using short8 = __attribute__((ext_vector_type(8))) short;
using f32x4  = __attribute__((ext_vector_type(4))) float;

static constexpr int   kNC    = 1026;   // n_fft + 2 (real S_ri cols)
static constexpr float kTwoPi = 6.283185307179586f;

#define GLDS(g, l) __builtin_amdgcn_global_load_lds(                       \
    (const __attribute__((address_space(1))) uint32_t*)(g),                \
    (__attribute__((address_space(3))) uint32_t*)(l), 16, 0, 0)

#define BAR()   { __builtin_amdgcn_sched_barrier(0); __builtin_amdgcn_s_barrier(); \
                  asm volatile("" ::: "memory"); }
#define LGKM0() { asm volatile("s_waitcnt lgkmcnt(0)" ::: "memory"); __builtin_amdgcn_sched_barrier(0); }
#define VM6()   { asm volatile("s_waitcnt vmcnt(6)"   ::: "memory"); __builtin_amdgcn_sched_barrier(0); }
#define VM0()   { asm volatile("s_waitcnt vmcnt(0)"   ::: "memory"); __builtin_amdgcn_sched_barrier(0); }

// ---------------------------------------------------------------- prep: x -> bf16
__global__ void cvt_x_k(const float* __restrict__ x, bf16* __restrict__ xb) {
    size_t i = ((size_t)blockIdx.x * 256 + threadIdx.x) * 8;
    float4 a = *(const float4*)(x + i);
    float4 c = *(const float4*)(x + i + 4);
    union { bf16 h[8]; uint4 u; } o;
    o.h[0] = __float2bfloat16(a.x); o.h[1] = __float2bfloat16(a.y);
    o.h[2] = __float2bfloat16(a.z); o.h[3] = __float2bfloat16(a.w);
    o.h[4] = __float2bfloat16(c.x); o.h[5] = __float2bfloat16(c.y);
    o.h[6] = __float2bfloat16(c.z); o.h[7] = __float2bfloat16(c.w);
    *(uint4*)(xb + i) = o.u;
}

// ------------------------------------------- prep: W -> Wr [1152][512] interleaved
__global__ void prep_w_k(const float* __restrict__ W, const float* __restrict__ b,
                         bf16* __restrict__ Wr, float* __restrict__ br) {
    int j = blockIdx.x;
    int col = -1;
    if (j < 1024)      col = (j & 1) ? 513 + (j >> 1) : (j >> 1);
    else if (j == 1024) col = 512;
    else if (j == 1025) col = 1025;
    for (int k = threadIdx.x; k < 512; k += 256) {
        float v = (col >= 0) ? W[(size_t)k * 1026 + col] : 0.0f;
        Wr[(size_t)j * 512 + k] = __float2bfloat16(v);
    }
    if (threadIdx.x == 0) br[j] = (col >= 0) ? b[col] : 0.0f;
}

// --------------------- prep: windowed irfft matrix Mw [1024 rows n][1088 cols kk]
__global__ void prep_m_k(bf16* __restrict__ Mw, float* __restrict__ w2) {
    int nrow = blockIdx.x;
    float wn = 0.5f - 0.5f * cosf(kTwoPi * (float)nrow / 1023.0f);  // numpy hanning
    for (int kk = threadIdx.x; kk < 1088; kk += 256) {
        float v = 0.0f;
        if (kk < 1026) {
            int k = kk >> 1;
            int mm = (k * nrow) & 1023;
            float ang = kTwoPi * (float)mm * (1.0f / 1024.0f);
            float alpha = (k == 0 || k == 512) ? 1.0f : 2.0f;
            float tw = (kk & 1) ? -sinf(ang) : cosf(ang);
            v = alpha * (1.0f / 1024.0f) * wn * tw;
        }
        Mw[(size_t)nrow * 1088 + kk] = __float2bfloat16(v);
    }
    if (threadIdx.x == 0) w2[nrow] = wn * wn;
}

// ------------------------------------- 256x128 triple-buffer single-barrier bf16 GEMM
// C = A(MxK) * B^T (B stored [n][k]); BK=64; 8 waves 4x2, per-wave 64x64 output.
// LDS: 3 slabs x (A 256x64 = 32KB + B 128x64 = 16KB) = 144 KiB, XOR-swizzled 16B slots.
// Per tile: {ds_read(t%3); stage(t+2 -> (t+2)%3); vmcnt(6); lgkmcnt(0); BAR; MMA}.
// Ledger: reads of slab X lgkm0-complete before own-iter BAR; stage into X only after
// that BAR; vmcnt(6) retires stage(t+1) (6+6 in flight). ONE barrier per K-tile.
template<int K, int LDO, int EPI, int NTL>
__global__ __launch_bounds__(512, 2)
void gemm3s_k(const bf16* __restrict__ A, const bf16* __restrict__ B,
              const float* __restrict__ bias, bf16* __restrict__ O)
{
    extern __shared__ __align__(16) bf16 lds[];   // 3 slabs x 24576 elems
    constexpr int NT = K / 64;

    const int tid  = threadIdx.x;
    const int w    = tid >> 6;
    const int lane = tid & 63;
    const int wr = w >> 1, wc = w & 1;            // wave grid 4(M) x 2(N)

    const int nwg  = gridDim.x;
    const int orig = blockIdx.x;
    const int bid  = (orig & 7) * (nwg >> 3) + (orig >> 3);   // XCD-contiguous
    const int nt = bid % NTL;                     // nt-minor: A-panel stays L2-hot
    const int mt = bid / NTL;
    const int row0 = mt * 256;
    const int col0 = nt * 128;

    const int srow  = lane >> 3;
    const int sslot = (lane & 7) ^ srow;          // pre-swizzled global 16B slot

    const bf16* gA0 = A + (size_t)(row0 + srow) * K + sslot * 8;
    const bf16* gB0 = B + (size_t)(col0 + srow) * K + sslot * 8;

    // 6 GLDS per wave per tile: 4 for A (rows w*32..+31), 2 for B (rows w*16..+15)
    auto stage = [&](int t, int s) {
        bf16* lA = lds + s * 24576;
        bf16* lB = lA + 16384;
        #pragma unroll
        for (int l = 0; l < 4; ++l) {
            const int c = w * 4 + l;
            GLDS(gA0 + (size_t)(8 * c) * K + (size_t)t * 64, lA + c * 512 + lane * 8);
        }
        #pragma unroll
        for (int l = 0; l < 2; ++l) {
            const int d = w * 2 + l;
            GLDS(gB0 + (size_t)(8 * d) * K + (size_t)t * 64, lB + d * 512 + lane * 8);
        }
    };

    short8 af[4][2], bq[4][2];
    auto ldregs = [&](int s) {
        const bf16* lA = lds + s * 24576;
        const bf16* lB = lA + 16384;
        #pragma unroll
        for (int fm = 0; fm < 4; ++fm)
            #pragma unroll
            for (int ks = 0; ks < 2; ++ks) {
                const int r  = wr * 64 + fm * 16 + (lane & 15);
                const int sl = (ks * 4 + (lane >> 4)) ^ (r & 7);
                af[fm][ks] = *(const short8*)(lA + r * 64 + sl * 8);
            }
        #pragma unroll
        for (int fn = 0; fn < 4; ++fn)
            #pragma unroll
            for (int ks = 0; ks < 2; ++ks) {
                const int r  = wc * 64 + fn * 16 + (lane & 15);
                const int sl = (ks * 4 + (lane >> 4)) ^ (r & 7);
                bq[fn][ks] = *(const short8*)(lB + r * 64 + sl * 8);
            }
    };

    f32x4 acc[4][4] = {};

    stage(0, 0);
    stage(1, 1);
    VM6();                                        // tile 0 resident
    BAR();

    for (int t = 0; t < NT; ++t) {
        const int tp = (t + 2 < NT) ? t + 2 : NT - 1;   // clamped prefetch
        ldregs(t % 3);
        stage(tp, (t + 2) % 3);
        VM6();                                    // retire stage(t+1)
        LGKM0();                                  // own reads of slab t%3 done
        BAR();                                    // t+1 visible; slab (t+2)%3 free
        __builtin_amdgcn_s_setprio(1);
        #pragma unroll
        for (int ks = 0; ks < 2; ++ks)
            #pragma unroll
            for (int fm = 0; fm < 4; ++fm)
                #pragma unroll
                for (int fn = 0; fn < 4; ++fn)
                    acc[fm][fn] = __builtin_amdgcn_mfma_f32_16x16x32_bf16(
                        af[fm][ks], bq[fn][ks], acc[fm][fn], 0, 0, 0);
        __builtin_amdgcn_s_setprio(0);
    }
    VM0();                                        // drain clamped garbage prefetches
    BAR();                                        // LDS free for epilogue

    // --------------------------- epilogue: acc -> LDS (swizzled) -> coalesced store
    char* eb = (char*)lds;                        // [256 rows][256 B]
    #pragma unroll
    for (int fm = 0; fm < 4; ++fm) {
        #pragma unroll
        for (int fn = 0; fn < 4; ++fn) {
            const int col = wc * 64 + fn * 16 + (lane & 15);     // 0..127 in tile
            const int n   = col0 + col;
            #pragma unroll
            for (int r = 0; r < 4; ++r) {
                const int row = wr * 64 + fm * 16 + (lane >> 4) * 4 + r;
                float v = acc[fm][fn][r];
                bf16 val;
                if constexpr (EPI == 1) {
                    v += bias[n];
                    float vo = __shfl_xor(v, 1);
                    float res = (n & 1) ? fminf(__expf(vo), 100.0f) * __sinf(v)
                                        : fminf(__expf(v), 100.0f) * __cosf(vo);
                    val = __float2bfloat16(n < kNC ? res : 0.0f);
                } else {
                    val = __float2bfloat16(v);
                }
                const int sw = (col >> 3) ^ (((row >> 2) & 7) << 1);
                *(bf16*)(eb + row * 256 + sw * 16 + (col & 7) * 2) = val;
            }
        }
    }
    asm volatile("s_waitcnt lgkmcnt(0)" ::: "memory");
    BAR();

    #pragma unroll
    for (int k2 = 0; k2 < 8; ++k2) {
        const int g   = tid + k2 * 512;           // 0..4095 16B-chunks
        const int row = g >> 4;
        const int s   = g & 15;
        const int sw  = s ^ (((row >> 2) & 7) << 1);
        short8 vv = *(const short8*)(eb + row * 256 + sw * 16);
        const int colg = col0 + s * 8;
        if (colg < LDO)                           // clip GEMM1's padding cols >= LDO
            *(short8*)(O + (size_t)(row0 + row) * LDO + colg) = vv;
    }
}

// --------------------------------------------- overlap-add gather, 8 outputs/thread
// 8,388,608 outputs / 8 per thread / 256 threads = 4096 blocks.
__global__ void ola_k(const bf16* __restrict__ frames, const float* __restrict__ w2g,
                      float* __restrict__ out) {
    __shared__ float w2[1024];
    for (int i = threadIdx.x; i < 1024; i += 256) w2[i] = w2g[i];
    __syncthreads();
    const int gid = blockIdx.x * 256 + threadIdx.x;
    const int o0  = gid * 8;
    const int b   = o0 >> 19;                     // 524288 outputs per batch
    const int oo  = o0 & 524287;
    const int s   = oo + 384;                     // multiple of 8
    const int tmax = s >> 8;
    float sum[8] = {}, env[8] = {};
    #pragma unroll
    for (int jj = 0; jj < 4; ++jj) {
        const int t = tmax - jj;
        if (t >= 0 && t < 2048) {
            const int n0 = s - (t << 8);          // in [0, 1016], multiple of 8
            short8 fv = *(const short8*)(frames + (((size_t)b * 2048 + t) << 10) + n0);
            #pragma unroll
            for (int e = 0; e < 8; ++e) {
                union { short u; bf16 h; } cv; cv.u = fv[e];
                sum[e] += __bfloat162float(cv.h);
                env[e] += w2[n0 + e];
            }
        }
    }
    float4 r0, r1;
    r0.x = sum[0] / (env[0] + 1e-11f); r0.y = sum[1] / (env[1] + 1e-11f);
    r0.z = sum[2] / (env[2] + 1e-11f); r0.w = sum[3] / (env[3] + 1e-11f);
    r1.x = sum[4] / (env[4] + 1e-11f); r1.y = sum[5] / (env[5] + 1e-11f);
    r1.z = sum[6] / (env[6] + 1e-11f); r1.w = sum[7] / (env[7] + 1e-11f);
    *(float4*)(out + o0)     = r0;
    *(float4*)(out + o0 + 4) = r1;
}

// ---------------------------------------------------------------------- launcher
extern "C" void kernel_launch(void* const* d_in, const int* in_sizes, int n_in,
                              void* d_out, int out_size, void* d_ws, size_t ws_size,
                              hipStream_t stream)
{
    const float* x = (const float*)d_in[0];
    const float* W = (const float*)d_in[1];
    const float* b = (const float*)d_in[2];
    float* out = (float*)d_out;

    char* ws = (char*)d_ws;
    size_t off = 0;
    auto alloc = [&](size_t bytes) { char* p = ws + off; off += (bytes + 255) & ~255ull; return p; };

    bf16*  Mw  = (bf16*) alloc(1024ull * 1088 * 2);
    float* w2  = (float*)alloc(1024 * 4);
    float* br  = (float*)alloc(1152 * 4);
    bf16*  Sri = (bf16*) alloc(32768ull * 1088 * 2);   // (Re,Im) interleaved
    char*  regC = alloc(67108864ull);
    bf16*  xb     = (bf16*)regC;
    bf16*  Wr     = (bf16*)(regC + 33554432ull);       // [1152][512]
    bf16*  frames = (bf16*)regC;                       // aliases xb+Wr after GEMM1

    hipFuncSetAttribute(reinterpret_cast<const void*>(gemm3s_k<512, 1088, 1, 9>),
                        hipFuncAttributeMaxDynamicSharedMemorySize, 147456);
    hipFuncSetAttribute(reinterpret_cast<const void*>(gemm3s_k<1088, 1024, 0, 8>),
                        hipFuncAttributeMaxDynamicSharedMemorySize, 147456);

    cvt_x_k <<<dim3(8192), dim3(256), 0, stream>>>(x, xb);
    prep_w_k<<<dim3(1152), dim3(256), 0, stream>>>(W, b, Wr, br);
    prep_m_k<<<dim3(1024), dim3(256), 0, stream>>>(Mw, w2);
    // GEMM1: (32768 x 1152) = xb @ Wr^T, fused exp/cos/sin -> Sri (LDO 1088)
    gemm3s_k<512, 1088, 1, 9> <<<dim3(1152), dim3(512), 147456, stream>>>(xb, Wr, br, Sri);
    // GEMM2: (32768 x 1024) = Sri @ Mw^T -> windowed frames
    gemm3s_k<1088, 1024, 0, 8><<<dim3(1024), dim3(512), 147456, stream>>>(Sri, Mw, nullptr, frames);
    ola_k   <<<dim3(4096),  dim3(256), 0, stream>>>(frames, w2, out);
    (void)in_sizes; (void)n_in; (void)out_size; (void)ws_size;
}